// Round 7
// baseline (276.765 us; speedup 1.0000x reference)
//
// R7: attribution round 2 — proj tiles x8 (grid-extended), logit x4 (atomics once),
// gather back to 1x (R2 exact). Completes the per-kernel time map.
#include <hip/hip_runtime.h>
#include <math.h>

#define N_NODES 10000
#define N_EDGES 320000
#define D 256
#define NEG_SLOPE 0.2f
#define BCAP 96
#define BLOCK 256
#define NF4 (N_NODES * D / 4)
#define NW4 (256 * 256 / 4)
#define NTILE_M 157
#define NTILES (NTILE_M * 12)
#define FILL_BLOCKS ((N_EDGES + BLOCK - 1) / BLOCK)
#define CPAD 66
#define PROJ_REPS 8
#define LOGIT_REPS 4

typedef unsigned short ushortT;
typedef __attribute__((ext_vector_type(8))) short bf16x8;
typedef __attribute__((ext_vector_type(4))) float f32x4;

__device__ __forceinline__ unsigned short f2bf(float f) {
  unsigned int u = __float_as_uint(f);
  u += 0x7FFFu + ((u >> 16) & 1u);
  return (unsigned short)(u >> 16);
}
__device__ __forceinline__ float bf2f(unsigned short u) {
  return __uint_as_float((unsigned int)u << 16);
}

typedef const __attribute__((address_space(1))) unsigned int* gas_ptr;
typedef __attribute__((address_space(3))) unsigned int* las_ptr;
__device__ __forceinline__ void gload16(const void* g, void* l) {
  __builtin_amdgcn_global_load_lds((gas_ptr)g, (las_ptr)l, 16, 0, 0);
}

__global__ void prep_kernel(const float* __restrict__ feat,
                            const float* __restrict__ Ws,
                            const float* __restrict__ Wt,
                            const float* __restrict__ Wfc,
                            ushortT* __restrict__ featb,
                            ushortT* __restrict__ Wcat,
                            int* __restrict__ cnt,
                            float* __restrict__ denom) {
  const int g = blockIdx.x * blockDim.x + threadIdx.x;
  if (g < NF4) {
    float4 v = ((const float4*)feat)[g];
    ushort4 u;
    u.x = f2bf(v.x); u.y = f2bf(v.y); u.z = f2bf(v.z); u.w = f2bf(v.w);
    ((ushort4*)featb)[g] = u;
    return;
  }
  const int gi = g - NF4;
  if (gi < 3 * NW4) {
    const float* W = (gi < NW4) ? Ws : ((gi < 2 * NW4) ? Wt : Wfc);
    const int off = gi - ((gi < NW4) ? 0 : ((gi < 2 * NW4) ? NW4 : 2 * NW4));
    float4 v = ((const float4*)W)[off];
    ushort4 u;
    u.x = f2bf(v.x); u.y = f2bf(v.y); u.z = f2bf(v.z); u.w = f2bf(v.w);
    ((ushort4*)Wcat)[gi] = u;
    return;
  }
  const int gn = gi - 3 * NW4;
  if (gn < N_NODES) {
    cnt[gn] = 0;
    denom[gn] = 0.f;
  }
}

// fill blocks unchanged (run once); proj tiles repeated PROJ_REPS x via grid
// extension (p = ext % NTILES). Duplicate tiles rewrite identical bytes.
__global__ __launch_bounds__(256, 2) void proj_fill_kernel(
    const ushortT* __restrict__ featb,
    const ushortT* __restrict__ Wcat,
    const int* __restrict__ src, const int* __restrict__ dst,
    int* __restrict__ cnt, int* __restrict__ src_b,
    ushortT* __restrict__ ps, ushortT* __restrict__ pt,
    ushortT* __restrict__ fcp) {
  __shared__ ushortT Als[64][D];
  __shared__ ushortT Bls[64][D];
  __shared__ ushortT Cls[64][CPAD];

  if (blockIdx.x < FILL_BLOCKS) {
    const int i = blockIdx.x * BLOCK + threadIdx.x;
    if (i < N_EDGES) {
      const int dn = dst[i];
      const int slot = atomicAdd(&cnt[dn], 1);
      if (slot < BCAP) src_b[dn * BCAP + slot] = src[i];
    }
    return;
  }
  const int p = (blockIdx.x - FILL_BLOCKS) % NTILES;   // rep probe
  const int m0 = (p / 12) * 64;
  const int by = p % 12;
  ushortT* outp = (by < 4) ? ps : ((by < 8) ? pt : fcp);
  const int col0 = (by & 3) * 64;
  const int n0 = by * 64;

  const int tid = threadIdx.x;
  const int wave = tid >> 6;
  const int lane = tid & 63;
  const int quad = lane >> 4;
  const int l16 = lane & 15;

  const int m_base_t = (wave & 1) * 32;
  const int wn = wave >> 1;

  {
    const int rl = lane >> 5;
    const int cph = lane & 31;
#pragma unroll
    for (int c = 0; c < 8; ++c) {
      const int r = wave * 16 + c * 2 + rl;
      const int clog = cph ^ (r & 7);
      gload16(featb + (size_t)(m0 + r) * D + clog * 8, &Als[wave * 16 + c * 2][0]);
      gload16(Wcat + (size_t)(n0 + r) * D + clog * 8, &Bls[wave * 16 + c * 2][0]);
    }
  }
  __syncthreads();

  f32x4 acc[2][2];
#pragma unroll
  for (int i = 0; i < 2; ++i)
#pragma unroll
    for (int j = 0; j < 2; ++j) acc[i][j] = (f32x4){0.f, 0.f, 0.f, 0.f};

  const int ar0 = m_base_t + l16;
  const int br0 = wn * 32 + l16;
  const int xa = ar0 & 7;
  const int xb = br0 & 7;
#pragma unroll
  for (int kk = 0; kk < 8; ++kk) {
    const int j = kk * 4 + quad;
    const int ea = (j ^ xa) * 8;
    const int eb = (j ^ xb) * 8;
    bf16x8 a0 = *(const bf16x8*)&Als[ar0][ea];
    bf16x8 a1 = *(const bf16x8*)&Als[ar0 + 16][ea];
    bf16x8 b0 = *(const bf16x8*)&Bls[br0][eb];
    bf16x8 b1 = *(const bf16x8*)&Bls[br0 + 16][eb];
    acc[0][0] = __builtin_amdgcn_mfma_f32_16x16x32_bf16(a0, b0, acc[0][0], 0, 0, 0);
    acc[0][1] = __builtin_amdgcn_mfma_f32_16x16x32_bf16(a0, b1, acc[0][1], 0, 0, 0);
    acc[1][0] = __builtin_amdgcn_mfma_f32_16x16x32_bf16(a1, b0, acc[1][0], 0, 0, 0);
    acc[1][1] = __builtin_amdgcn_mfma_f32_16x16x32_bf16(a1, b1, acc[1][1], 0, 0, 0);
  }

  // C/D layout: col = lane&15, row = quad*4 + reg [m89/m91]
#pragma unroll
  for (int mi = 0; mi < 2; ++mi)
#pragma unroll
    for (int r = 0; r < 4; ++r) {
      const int row = m_base_t + mi * 16 + quad * 4 + r;
#pragma unroll
      for (int ni = 0; ni < 2; ++ni)
        Cls[row][wn * 32 + ni * 16 + l16] = f2bf(acc[mi][ni][r]);
    }
  __syncthreads();
#pragma unroll
  for (int it = 0; it < 2; ++it) {
    const int idx = tid + it * 256;
    const int row = idx >> 3;
    const int cc = (idx & 7) * 8;
    const int grow = m0 + row;
    if (grow < N_NODES)
      *(bf16x8*)(outp + (size_t)grow * D + col0 + cc) = *(const bf16x8*)&Cls[row][cc];
  }
}

// Wave per node + LOGIT_REPS probe: body repeated, expv rewrites idempotent,
// atomicAdd(denom) only on rep 0 (keeps denom exact).
__global__ __launch_bounds__(256) void logit_bucket_kernel(
    const ushortT* __restrict__ ps,
    const ushortT* __restrict__ pt,
    const int* __restrict__ cnt,
    const int* __restrict__ src_b,
    const float* __restrict__ Wattn,
    float* __restrict__ expv_b,
    float* __restrict__ denom) {
  const int wave = threadIdx.x >> 6;
  const int n = blockIdx.x * 4 + wave;
  if (n >= N_NODES) return;
  const int cn = min(cnt[n], BCAP);
  if (cn == 0) return;
  const int lane = threadIdx.x & 63;
  const int half = lane >> 5;
  const int l32 = lane & 31;
  const int base = n * BCAP;

  bf16x8 bu = *(const bf16x8*)(pt + (size_t)n * D + l32 * 8);
  float b[8], w[8];
  const float4 w0 = *(const float4*)(Wattn + l32 * 8);
  const float4 w1 = *(const float4*)(Wattn + l32 * 8 + 4);
  w[0] = w0.x; w[1] = w0.y; w[2] = w0.z; w[3] = w0.w;
  w[4] = w1.x; w[5] = w1.y; w[6] = w1.z; w[7] = w1.w;
#pragma unroll
  for (int i = 0; i < 8; ++i) b[i] = bf2f((unsigned short)bu[i]);

  for (int rep = 0; rep < LOGIT_REPS; ++rep) {
    asm volatile("" ::: "memory");   // forbid cross-rep CSE (probe integrity)
    int j = half;
    for (; j + 6 < cn; j += 8) {
      const int s0 = src_b[base + j];
      const int s1 = src_b[base + j + 2];
      const int s2 = src_b[base + j + 4];
      const int s3 = src_b[base + j + 6];
      bf16x8 au0 = *(const bf16x8*)(ps + (size_t)s0 * D + l32 * 8);
      bf16x8 au1 = *(const bf16x8*)(ps + (size_t)s1 * D + l32 * 8);
      bf16x8 au2 = *(const bf16x8*)(ps + (size_t)s2 * D + l32 * 8);
      bf16x8 au3 = *(const bf16x8*)(ps + (size_t)s3 * D + l32 * 8);
      float sum0 = 0.f, sum1 = 0.f, sum2 = 0.f, sum3 = 0.f;
#pragma unroll
      for (int i = 0; i < 8; ++i) {
        float z0 = bf2f((unsigned short)au0[i]) + b[i];
        float z1 = bf2f((unsigned short)au1[i]) + b[i];
        float z2 = bf2f((unsigned short)au2[i]) + b[i];
        float z3 = bf2f((unsigned short)au3[i]) + b[i];
        z0 = fmaxf(z0, NEG_SLOPE * z0);
        z1 = fmaxf(z1, NEG_SLOPE * z1);
        z2 = fmaxf(z2, NEG_SLOPE * z2);
        z3 = fmaxf(z3, NEG_SLOPE * z3);
        sum0 = fmaf(w[i], z0, sum0);
        sum1 = fmaf(w[i], z1, sum1);
        sum2 = fmaf(w[i], z2, sum2);
        sum3 = fmaf(w[i], z3, sum3);
      }
#pragma unroll
      for (int off = 16; off > 0; off >>= 1) {
        sum0 += __shfl_down(sum0, off, 32);
        sum1 += __shfl_down(sum1, off, 32);
        sum2 += __shfl_down(sum2, off, 32);
        sum3 += __shfl_down(sum3, off, 32);
      }
      if (l32 == 0) {
        float ex0 = __expf(sum0), ex1 = __expf(sum1);
        float ex2 = __expf(sum2), ex3 = __expf(sum3);
        expv_b[base + j] = ex0;
        expv_b[base + j + 2] = ex1;
        expv_b[base + j + 4] = ex2;
        expv_b[base + j + 6] = ex3;
        if (rep == 0) {
          atomicAdd(&denom[s0], ex0);
          atomicAdd(&denom[s1], ex1);
          atomicAdd(&denom[s2], ex2);
          atomicAdd(&denom[s3], ex3);
        }
      }
    }
    for (; j < cn; j += 2) {
      const int s = src_b[base + j];
      bf16x8 au = *(const bf16x8*)(ps + (size_t)s * D + l32 * 8);
      float sum = 0.f;
#pragma unroll
      for (int i = 0; i < 8; ++i) {
        float z = bf2f((unsigned short)au[i]) + b[i];
        z = fmaxf(z, NEG_SLOPE * z);
        sum = fmaf(w[i], z, sum);
      }
#pragma unroll
      for (int off = 16; off > 0; off >>= 1) sum += __shfl_down(sum, off, 32);
      if (l32 == 0) {
        float ex = __expf(sum);
        expv_b[base + j] = ex;
        if (rep == 0) atomicAdd(&denom[s], ex);
      }
    }
  }
}

// gather: exact R2 body (1x).
__global__ __launch_bounds__(256) void gather_agg_kernel(
    const ushortT* __restrict__ fcp,
    const int* __restrict__ cnt,
    const int* __restrict__ src_b,
    const float* __restrict__ expv_b,
    const float* __restrict__ denom,
    const float* __restrict__ b_fc,
    float* __restrict__ out) {
  const int wave = threadIdx.x >> 6;
  const int n = blockIdx.x * 4 + wave;
  if (n >= N_NODES) return;
  const int lane = threadIdx.x & 63;
  const int half = lane >> 5;
  const int l32 = lane & 31;
  const int cn = min(cnt[n], BCAP);
  const int base = n * BCAP;

  float acc[8];
#pragma unroll
  for (int i = 0; i < 8; ++i) acc[i] = 0.f;

  int j = half;
  for (; j + 6 < cn; j += 8) {
    const int s0 = src_b[base + j];
    const int s1 = src_b[base + j + 2];
    const int s2 = src_b[base + j + 4];
    const int s3 = src_b[base + j + 6];
    const float a0 = expv_b[base + j] / denom[s0];
    const float a1 = expv_b[base + j + 2] / denom[s1];
    const float a2 = expv_b[base + j + 4] / denom[s2];
    const float a3 = expv_b[base + j + 6] / denom[s3];
    bf16x8 f0 = *(const bf16x8*)(fcp + (size_t)s0 * D + l32 * 8);
    bf16x8 f1 = *(const bf16x8*)(fcp + (size_t)s1 * D + l32 * 8);
    bf16x8 f2 = *(const bf16x8*)(fcp + (size_t)s2 * D + l32 * 8);
    bf16x8 f3 = *(const bf16x8*)(fcp + (size_t)s3 * D + l32 * 8);
#pragma unroll
    for (int i = 0; i < 8; ++i) {
      acc[i] = fmaf(a0, bf2f((unsigned short)f0[i]), acc[i]);
      acc[i] = fmaf(a1, bf2f((unsigned short)f1[i]), acc[i]);
      acc[i] = fmaf(a2, bf2f((unsigned short)f2[i]), acc[i]);
      acc[i] = fmaf(a3, bf2f((unsigned short)f3[i]), acc[i]);
    }
  }
  for (; j < cn; j += 2) {
    const int s = src_b[base + j];
    const float a = expv_b[base + j] / denom[s];
    bf16x8 fu = *(const bf16x8*)(fcp + (size_t)s * D + l32 * 8);
#pragma unroll
    for (int i = 0; i < 8; ++i)
      acc[i] = fmaf(a, bf2f((unsigned short)fu[i]), acc[i]);
  }
#pragma unroll
  for (int i = 0; i < 8; ++i) acc[i] += __shfl_xor(acc[i], 32);
  if (half == 0) {
    const float4 bf0 = *(const float4*)(b_fc + l32 * 8);
    const float4 bf1 = *(const float4*)(b_fc + l32 * 8 + 4);
    float4 o0 = make_float4(acc[0] + bf0.x, acc[1] + bf0.y, acc[2] + bf0.z, acc[3] + bf0.w);
    float4 o1 = make_float4(acc[4] + bf1.x, acc[5] + bf1.y, acc[6] + bf1.z, acc[7] + bf1.w);
    *(float4*)(out + (size_t)n * D + l32 * 8) = o0;
    *(float4*)(out + (size_t)n * D + l32 * 8 + 4) = o1;
  }
}

extern "C" void kernel_launch(void* const* d_in, const int* in_sizes, int n_in,
                              void* d_out, int out_size, void* d_ws, size_t ws_size,
                              hipStream_t stream) {
  const float* feat  = (const float*)d_in[0];
  const int*   src   = (const int*)d_in[1];
  const int*   dst   = (const int*)d_in[2];
  const float* Ws    = (const float*)d_in[3];
  const float* Wt    = (const float*)d_in[4];
  const float* Wattn = (const float*)d_in[5];
  const float* Wfc   = (const float*)d_in[6];
  const float* bfc   = (const float*)d_in[7];
  float* out = (float*)d_out;

  ushortT* ps    = (ushortT*)d_ws;
  ushortT* pt    = ps + (size_t)N_NODES * D;
  ushortT* fcp   = pt + (size_t)N_NODES * D;
  ushortT* featb = fcp + (size_t)N_NODES * D;
  ushortT* Wcat  = featb + (size_t)N_NODES * D;
  float* expv_b  = (float*)(Wcat + (size_t)768 * 256);
  float* denom   = expv_b + (size_t)N_NODES * BCAP;
  int*   cnt     = (int*)(denom + N_NODES);
  int*   src_b   = cnt + N_NODES;

  const int prep_items = NF4 + 3 * NW4 + N_NODES;
  const int nodeblocks = (N_NODES + 3) / 4;
  prep_kernel<<<(prep_items + BLOCK - 1) / BLOCK, BLOCK, 0, stream>>>(
      feat, Ws, Wt, Wfc, featb, Wcat, cnt, denom);
  proj_fill_kernel<<<FILL_BLOCKS + PROJ_REPS * NTILES, BLOCK, 0, stream>>>(
      featb, Wcat, src, dst, cnt, src_b, ps, pt, fcp);
  logit_bucket_kernel<<<nodeblocks, BLOCK, 0, stream>>>(ps, pt, cnt, src_b, Wattn, expv_b, denom);
  gather_agg_kernel<<<nodeblocks, BLOCK, 0, stream>>>(fcp, cnt, src_b, expv_b, denom, bfc, out);
}

// Round 8
// 175.289 us; speedup vs baseline: 1.5789x; 1.5789x over previous
//
// R8: proj B-operand direct-to-reg (drop Bls, 3 blocks/CU) + vectorized bucket
// loads (int4/float4 contiguous 4-edge chains) in logit/gather + v_rcp alpha.
#include <hip/hip_runtime.h>
#include <math.h>

#define N_NODES 10000
#define N_EDGES 320000
#define D 256
#define NEG_SLOPE 0.2f
#define BCAP 96
#define BLOCK 256
#define NF4 (N_NODES * D / 4)
#define NW4 (256 * 256 / 4)
#define NTILE_M 157
#define NTILES (NTILE_M * 12)
#define FILL_BLOCKS ((N_EDGES + BLOCK - 1) / BLOCK)
#define CPAD 66

typedef unsigned short ushortT;
typedef __attribute__((ext_vector_type(8))) short bf16x8;
typedef __attribute__((ext_vector_type(4))) float f32x4;

__device__ __forceinline__ unsigned short f2bf(float f) {
  unsigned int u = __float_as_uint(f);
  u += 0x7FFFu + ((u >> 16) & 1u);
  return (unsigned short)(u >> 16);
}
__device__ __forceinline__ float bf2f(unsigned short u) {
  return __uint_as_float((unsigned int)u << 16);
}
// 1-inst reciprocal (~1 ulp) — alpha tolerance is far looser than this
__device__ __forceinline__ float fastrcp(float x) {
  float r;
  asm volatile("v_rcp_f32 %0, %1" : "=v"(r) : "v"(x));
  return r;
}

typedef const __attribute__((address_space(1))) unsigned int* gas_ptr;
typedef __attribute__((address_space(3))) unsigned int* las_ptr;
__device__ __forceinline__ void gload16(const void* g, void* l) {
  __builtin_amdgcn_global_load_lds((gas_ptr)g, (las_ptr)l, 16, 0, 0);
}

__global__ void prep_kernel(const float* __restrict__ feat,
                            const float* __restrict__ Ws,
                            const float* __restrict__ Wt,
                            const float* __restrict__ Wfc,
                            ushortT* __restrict__ featb,
                            ushortT* __restrict__ Wcat,
                            int* __restrict__ cnt,
                            float* __restrict__ denom) {
  const int g = blockIdx.x * blockDim.x + threadIdx.x;
  if (g < NF4) {
    float4 v = ((const float4*)feat)[g];
    ushort4 u;
    u.x = f2bf(v.x); u.y = f2bf(v.y); u.z = f2bf(v.z); u.w = f2bf(v.w);
    ((ushort4*)featb)[g] = u;
    return;
  }
  const int gi = g - NF4;
  if (gi < 3 * NW4) {
    const float* W = (gi < NW4) ? Ws : ((gi < 2 * NW4) ? Wt : Wfc);
    const int off = gi - ((gi < NW4) ? 0 : ((gi < 2 * NW4) ? NW4 : 2 * NW4));
    float4 v = ((const float4*)W)[off];
    ushort4 u;
    u.x = f2bf(v.x); u.y = f2bf(v.y); u.z = f2bf(v.z); u.w = f2bf(v.w);
    ((ushort4*)Wcat)[gi] = u;
    return;
  }
  const int gn = gi - 3 * NW4;
  if (gn < N_NODES) {
    cnt[gn] = 0;
    denom[gn] = 0.f;
  }
}

// R8 proj: A staged via gload_lds+XOR swizzle (unchanged); B (weights, L2-hot)
// loaded directly to registers — no Bls. LDS 41 KB -> 3 blocks/CU.
__global__ __launch_bounds__(256, 3) void proj_fill_kernel(
    const ushortT* __restrict__ featb,
    const ushortT* __restrict__ Wcat,
    const int* __restrict__ src, const int* __restrict__ dst,
    int* __restrict__ cnt, int* __restrict__ src_b,
    ushortT* __restrict__ ps, ushortT* __restrict__ pt,
    ushortT* __restrict__ fcp) {
  __shared__ ushortT Als[64][D];      // 32 KB
  __shared__ ushortT Cls[64][CPAD];   // 8.25 KB

  if (blockIdx.x < FILL_BLOCKS) {
    const int i = blockIdx.x * BLOCK + threadIdx.x;
    if (i < N_EDGES) {
      const int dn = dst[i];
      const int slot = atomicAdd(&cnt[dn], 1);
      if (slot < BCAP) src_b[dn * BCAP + slot] = src[i];
    }
    return;
  }
  const int p = blockIdx.x - FILL_BLOCKS;
  const int m0 = (p / 12) * 64;
  const int by = p % 12;
  ushortT* outp = (by < 4) ? ps : ((by < 8) ? pt : fcp);
  const int col0 = (by & 3) * 64;
  const int n0 = by * 64;

  const int tid = threadIdx.x;
  const int wave = tid >> 6;
  const int lane = tid & 63;
  const int quad = lane >> 4;
  const int l16 = lane & 15;

  const int m_base_t = (wave & 1) * 32;
  const int wn = wave >> 1;
  const int br0 = wn * 32 + l16;

  // B fragments straight from global (row n0+br0 / +16, cols kk*32+quad*8).
  // Issued first; the staging barrier's vmcnt(0) drains them too.
  bf16x8 b0r[8], b1r[8];
#pragma unroll
  for (int kk = 0; kk < 8; ++kk) {
    b0r[kk] = *(const bf16x8*)(Wcat + (size_t)(n0 + br0) * D + kk * 32 + quad * 8);
    b1r[kk] = *(const bf16x8*)(Wcat + (size_t)(n0 + br0 + 16) * D + kk * 32 + quad * 8);
  }

  // A staging: async gload_lds, XOR-swizzled source (rule #21).
  {
    const int rl = lane >> 5;
    const int cph = lane & 31;
#pragma unroll
    for (int c = 0; c < 8; ++c) {
      const int r = wave * 16 + c * 2 + rl;
      const int clog = cph ^ (r & 7);
      gload16(featb + (size_t)(m0 + r) * D + clog * 8, &Als[wave * 16 + c * 2][0]);
    }
  }
  __syncthreads();

  f32x4 acc[2][2];
#pragma unroll
  for (int i = 0; i < 2; ++i)
#pragma unroll
    for (int j = 0; j < 2; ++j) acc[i][j] = (f32x4){0.f, 0.f, 0.f, 0.f};

  const int ar0 = m_base_t + l16;
  const int xa = ar0 & 7;
#pragma unroll
  for (int kk = 0; kk < 8; ++kk) {
    const int ea = ((kk * 4 + quad) ^ xa) * 8;
    bf16x8 a0 = *(const bf16x8*)&Als[ar0][ea];
    bf16x8 a1 = *(const bf16x8*)&Als[ar0 + 16][ea];
    acc[0][0] = __builtin_amdgcn_mfma_f32_16x16x32_bf16(a0, b0r[kk], acc[0][0], 0, 0, 0);
    acc[0][1] = __builtin_amdgcn_mfma_f32_16x16x32_bf16(a0, b1r[kk], acc[0][1], 0, 0, 0);
    acc[1][0] = __builtin_amdgcn_mfma_f32_16x16x32_bf16(a1, b0r[kk], acc[1][0], 0, 0, 0);
    acc[1][1] = __builtin_amdgcn_mfma_f32_16x16x32_bf16(a1, b1r[kk], acc[1][1], 0, 0, 0);
  }

  // C/D layout: col = lane&15, row = quad*4 + reg [m89/m91]
#pragma unroll
  for (int mi = 0; mi < 2; ++mi)
#pragma unroll
    for (int r = 0; r < 4; ++r) {
      const int row = m_base_t + mi * 16 + quad * 4 + r;
#pragma unroll
      for (int ni = 0; ni < 2; ++ni)
        Cls[row][wn * 32 + ni * 16 + l16] = f2bf(acc[mi][ni][r]);
    }
  __syncthreads();
#pragma unroll
  for (int it = 0; it < 2; ++it) {
    const int idx = tid + it * 256;
    const int row = idx >> 3;
    const int cc = (idx & 7) * 8;
    const int grow = m0 + row;
    if (grow < N_NODES)
      *(bf16x8*)(outp + (size_t)grow * D + col0 + cc) = *(const bf16x8*)&Cls[row][cc];
  }
}

// Wave per node; contiguous 4-edge chain blocks (half h: j = h*4 + 8k) ->
// int4 src / float4 expv; tail stride-2.
__global__ __launch_bounds__(256) void logit_bucket_kernel(
    const ushortT* __restrict__ ps,
    const ushortT* __restrict__ pt,
    const int* __restrict__ cnt,
    const int* __restrict__ src_b,
    const float* __restrict__ Wattn,
    float* __restrict__ expv_b,
    float* __restrict__ denom) {
  const int wave = threadIdx.x >> 6;
  const int n = blockIdx.x * 4 + wave;
  if (n >= N_NODES) return;
  const int cn = min(cnt[n], BCAP);
  if (cn == 0) return;
  const int lane = threadIdx.x & 63;
  const int half = lane >> 5;
  const int l32 = lane & 31;
  const int base = n * BCAP;

  bf16x8 bu = *(const bf16x8*)(pt + (size_t)n * D + l32 * 8);
  float b[8], w[8];
  const float4 w0 = *(const float4*)(Wattn + l32 * 8);
  const float4 w1 = *(const float4*)(Wattn + l32 * 8 + 4);
  w[0] = w0.x; w[1] = w0.y; w[2] = w0.z; w[3] = w0.w;
  w[4] = w1.x; w[5] = w1.y; w[6] = w1.z; w[7] = w1.w;
#pragma unroll
  for (int i = 0; i < 8; ++i) b[i] = bf2f((unsigned short)bu[i]);

  const int cn4 = cn & ~7;           // region covered by 4-edge blocks
  for (int j = half * 4; j < cn4; j += 8) {
    const int4 s4 = *(const int4*)(src_b + base + j);   // base%4==0, j%4==0
    bf16x8 au0 = *(const bf16x8*)(ps + (size_t)s4.x * D + l32 * 8);
    bf16x8 au1 = *(const bf16x8*)(ps + (size_t)s4.y * D + l32 * 8);
    bf16x8 au2 = *(const bf16x8*)(ps + (size_t)s4.z * D + l32 * 8);
    bf16x8 au3 = *(const bf16x8*)(ps + (size_t)s4.w * D + l32 * 8);
    float sum0 = 0.f, sum1 = 0.f, sum2 = 0.f, sum3 = 0.f;
#pragma unroll
    for (int i = 0; i < 8; ++i) {
      float z0 = bf2f((unsigned short)au0[i]) + b[i];
      float z1 = bf2f((unsigned short)au1[i]) + b[i];
      float z2 = bf2f((unsigned short)au2[i]) + b[i];
      float z3 = bf2f((unsigned short)au3[i]) + b[i];
      z0 = fmaxf(z0, NEG_SLOPE * z0);
      z1 = fmaxf(z1, NEG_SLOPE * z1);
      z2 = fmaxf(z2, NEG_SLOPE * z2);
      z3 = fmaxf(z3, NEG_SLOPE * z3);
      sum0 = fmaf(w[i], z0, sum0);
      sum1 = fmaf(w[i], z1, sum1);
      sum2 = fmaf(w[i], z2, sum2);
      sum3 = fmaf(w[i], z3, sum3);
    }
#pragma unroll
    for (int off = 16; off > 0; off >>= 1) {
      sum0 += __shfl_down(sum0, off, 32);
      sum1 += __shfl_down(sum1, off, 32);
      sum2 += __shfl_down(sum2, off, 32);
      sum3 += __shfl_down(sum3, off, 32);
    }
    if (l32 == 0) {
      float ex0 = __expf(sum0), ex1 = __expf(sum1);
      float ex2 = __expf(sum2), ex3 = __expf(sum3);
      *(float4*)(expv_b + base + j) = make_float4(ex0, ex1, ex2, ex3);
      atomicAdd(&denom[s4.x], ex0);
      atomicAdd(&denom[s4.y], ex1);
      atomicAdd(&denom[s4.z], ex2);
      atomicAdd(&denom[s4.w], ex3);
    }
  }
  for (int j = cn4 + half; j < cn; j += 2) {
    const int s = src_b[base + j];
    bf16x8 au = *(const bf16x8*)(ps + (size_t)s * D + l32 * 8);
    float sum = 0.f;
#pragma unroll
    for (int i = 0; i < 8; ++i) {
      float z = bf2f((unsigned short)au[i]) + b[i];
      z = fmaxf(z, NEG_SLOPE * z);
      sum = fmaf(w[i], z, sum);
    }
#pragma unroll
    for (int off = 16; off > 0; off >>= 1) sum += __shfl_down(sum, off, 32);
    if (l32 == 0) {
      float ex = __expf(sum);
      expv_b[base + j] = ex;
      atomicAdd(&denom[s], ex);
    }
  }
}

// Wave per node; contiguous 4-edge blocks -> int4/float4 loads; v_rcp alpha.
__global__ __launch_bounds__(256) void gather_agg_kernel(
    const ushortT* __restrict__ fcp,
    const int* __restrict__ cnt,
    const int* __restrict__ src_b,
    const float* __restrict__ expv_b,
    const float* __restrict__ denom,
    const float* __restrict__ b_fc,
    float* __restrict__ out) {
  const int wave = threadIdx.x >> 6;
  const int n = blockIdx.x * 4 + wave;
  if (n >= N_NODES) return;
  const int lane = threadIdx.x & 63;
  const int half = lane >> 5;
  const int l32 = lane & 31;
  const int cn = min(cnt[n], BCAP);
  const int base = n * BCAP;

  float acc[8];
#pragma unroll
  for (int i = 0; i < 8; ++i) acc[i] = 0.f;

  const int cn4 = cn & ~7;
  for (int j = half * 4; j < cn4; j += 8) {
    const int4 s4 = *(const int4*)(src_b + base + j);
    const float4 e4 = *(const float4*)(expv_b + base + j);
    const float a0 = e4.x * fastrcp(denom[s4.x]);
    const float a1 = e4.y * fastrcp(denom[s4.y]);
    const float a2 = e4.z * fastrcp(denom[s4.z]);
    const float a3 = e4.w * fastrcp(denom[s4.w]);
    bf16x8 f0 = *(const bf16x8*)(fcp + (size_t)s4.x * D + l32 * 8);
    bf16x8 f1 = *(const bf16x8*)(fcp + (size_t)s4.y * D + l32 * 8);
    bf16x8 f2 = *(const bf16x8*)(fcp + (size_t)s4.z * D + l32 * 8);
    bf16x8 f3 = *(const bf16x8*)(fcp + (size_t)s4.w * D + l32 * 8);
#pragma unroll
    for (int i = 0; i < 8; ++i) {
      acc[i] = fmaf(a0, bf2f((unsigned short)f0[i]), acc[i]);
      acc[i] = fmaf(a1, bf2f((unsigned short)f1[i]), acc[i]);
      acc[i] = fmaf(a2, bf2f((unsigned short)f2[i]), acc[i]);
      acc[i] = fmaf(a3, bf2f((unsigned short)f3[i]), acc[i]);
    }
  }
  for (int j = cn4 + half; j < cn; j += 2) {
    const int s = src_b[base + j];
    const float a = expv_b[base + j] * fastrcp(denom[s]);
    bf16x8 fu = *(const bf16x8*)(fcp + (size_t)s * D + l32 * 8);
#pragma unroll
    for (int i = 0; i < 8; ++i)
      acc[i] = fmaf(a, bf2f((unsigned short)fu[i]), acc[i]);
  }
#pragma unroll
  for (int i = 0; i < 8; ++i) acc[i] += __shfl_xor(acc[i], 32);
  if (half == 0) {
    const float4 bf0 = *(const float4*)(b_fc + l32 * 8);
    const float4 bf1 = *(const float4*)(b_fc + l32 * 8 + 4);
    float4 o0 = make_float4(acc[0] + bf0.x, acc[1] + bf0.y, acc[2] + bf0.z, acc[3] + bf0.w);
    float4 o1 = make_float4(acc[4] + bf1.x, acc[5] + bf1.y, acc[6] + bf1.z, acc[7] + bf1.w);
    *(float4*)(out + (size_t)n * D + l32 * 8) = o0;
    *(float4*)(out + (size_t)n * D + l32 * 8 + 4) = o1;
  }
}

extern "C" void kernel_launch(void* const* d_in, const int* in_sizes, int n_in,
                              void* d_out, int out_size, void* d_ws, size_t ws_size,
                              hipStream_t stream) {
  const float* feat  = (const float*)d_in[0];
  const int*   src   = (const int*)d_in[1];
  const int*   dst   = (const int*)d_in[2];
  const float* Ws    = (const float*)d_in[3];
  const float* Wt    = (const float*)d_in[4];
  const float* Wattn = (const float*)d_in[5];
  const float* Wfc   = (const float*)d_in[6];
  const float* bfc   = (const float*)d_in[7];
  float* out = (float*)d_out;

  ushortT* ps    = (ushortT*)d_ws;
  ushortT* pt    = ps + (size_t)N_NODES * D;
  ushortT* fcp   = pt + (size_t)N_NODES * D;
  ushortT* featb = fcp + (size_t)N_NODES * D;
  ushortT* Wcat  = featb + (size_t)N_NODES * D;
  float* expv_b  = (float*)(Wcat + (size_t)768 * 256);
  float* denom   = expv_b + (size_t)N_NODES * BCAP;
  int*   cnt     = (int*)(denom + N_NODES);
  int*   src_b   = cnt + N_NODES;

  const int prep_items = NF4 + 3 * NW4 + N_NODES;
  const int nodeblocks = (N_NODES + 3) / 4;
  prep_kernel<<<(prep_items + BLOCK - 1) / BLOCK, BLOCK, 0, stream>>>(
      feat, Ws, Wt, Wfc, featb, Wcat, cnt, denom);
  proj_fill_kernel<<<FILL_BLOCKS + NTILES, BLOCK, 0, stream>>>(
      featb, Wcat, src, dst, cnt, src_b, ps, pt, fcp);
  logit_bucket_kernel<<<nodeblocks, BLOCK, 0, stream>>>(ps, pt, cnt, src_b, Wattn, expv_b, denom);
  gather_agg_kernel<<<nodeblocks, BLOCK, 0, stream>>>(fcp, cnt, src_b, expv_b, denom, bfc, out);
}

// Round 9
// 161.089 us; speedup vs baseline: 1.7181x; 1.0882x over previous
//
// R9 = R2 exact structure + unbundled VALU trims in bucket kernels only:
// (1) bf16 pair-unpack (1 VALU/elem), (2) v_rcp_f32 alpha. No memory-pattern
// or grid changes vs R2 (162.1 µs best).
#include <hip/hip_runtime.h>
#include <math.h>

#define N_NODES 10000
#define N_EDGES 320000
#define D 256
#define NEG_SLOPE 0.2f
#define BCAP 96
#define BLOCK 256
#define NF4 (N_NODES * D / 4)
#define NW4 (256 * 256 / 4)
#define NTILE_M 157
#define NTILES (NTILE_M * 12)
#define FILL_BLOCKS ((N_EDGES + BLOCK - 1) / BLOCK)
#define CPAD 66

typedef unsigned short ushortT;
typedef __attribute__((ext_vector_type(8))) short bf16x8;
typedef __attribute__((ext_vector_type(4))) float f32x4;

__device__ __forceinline__ unsigned short f2bf(float f) {
  unsigned int u = __float_as_uint(f);
  u += 0x7FFFu + ((u >> 16) & 1u);
  return (unsigned short)(u >> 16);
}
__device__ __forceinline__ float bf2f(unsigned short u) {
  return __uint_as_float((unsigned int)u << 16);
}
// bf16 pair-unpack: word w holds elems {2k (low16), 2k+1 (high16)}
__device__ __forceinline__ float blo(int w) {
  return __uint_as_float((unsigned int)w << 16);
}
__device__ __forceinline__ float bhi(int w) {
  return __uint_as_float((unsigned int)w & 0xFFFF0000u);
}
// 1-inst reciprocal (~1 ulp); non-volatile so the scheduler can move/CSE it
__device__ __forceinline__ float fastrcp(float x) {
  float r;
  asm("v_rcp_f32 %0, %1" : "=v"(r) : "v"(x));
  return r;
}

typedef const __attribute__((address_space(1))) unsigned int* gas_ptr;
typedef __attribute__((address_space(3))) unsigned int* las_ptr;
__device__ __forceinline__ void gload16(const void* g, void* l) {
  __builtin_amdgcn_global_load_lds((gas_ptr)g, (las_ptr)l, 16, 0, 0);
}

__global__ void prep_kernel(const float* __restrict__ feat,
                            const float* __restrict__ Ws,
                            const float* __restrict__ Wt,
                            const float* __restrict__ Wfc,
                            ushortT* __restrict__ featb,
                            ushortT* __restrict__ Wcat,
                            int* __restrict__ cnt,
                            float* __restrict__ denom) {
  const int g = blockIdx.x * blockDim.x + threadIdx.x;
  if (g < NF4) {
    float4 v = ((const float4*)feat)[g];
    ushort4 u;
    u.x = f2bf(v.x); u.y = f2bf(v.y); u.z = f2bf(v.z); u.w = f2bf(v.w);
    ((ushort4*)featb)[g] = u;
    return;
  }
  const int gi = g - NF4;
  if (gi < 3 * NW4) {
    const float* W = (gi < NW4) ? Ws : ((gi < 2 * NW4) ? Wt : Wfc);
    const int off = gi - ((gi < NW4) ? 0 : ((gi < 2 * NW4) ? NW4 : 2 * NW4));
    float4 v = ((const float4*)W)[off];
    ushort4 u;
    u.x = f2bf(v.x); u.y = f2bf(v.y); u.z = f2bf(v.z); u.w = f2bf(v.w);
    ((ushort4*)Wcat)[gi] = u;
    return;
  }
  const int gn = gi - 3 * NW4;
  if (gn < N_NODES) {
    cnt[gn] = 0;
    denom[gn] = 0.f;
  }
}

// R2-exact: fill blocks + MFMA proj (A and B staged via gload_lds + XOR swizzle).
__global__ __launch_bounds__(256, 2) void proj_fill_kernel(
    const ushortT* __restrict__ featb,
    const ushortT* __restrict__ Wcat,
    const int* __restrict__ src, const int* __restrict__ dst,
    int* __restrict__ cnt, int* __restrict__ src_b,
    ushortT* __restrict__ ps, ushortT* __restrict__ pt,
    ushortT* __restrict__ fcp) {
  __shared__ ushortT Als[64][D];
  __shared__ ushortT Bls[64][D];
  __shared__ ushortT Cls[64][CPAD];

  if (blockIdx.x < FILL_BLOCKS) {
    const int i = blockIdx.x * BLOCK + threadIdx.x;
    if (i < N_EDGES) {
      const int dn = dst[i];
      const int slot = atomicAdd(&cnt[dn], 1);
      if (slot < BCAP) src_b[dn * BCAP + slot] = src[i];
    }
    return;
  }
  const int p = blockIdx.x - FILL_BLOCKS;
  const int m0 = (p / 12) * 64;
  const int by = p % 12;
  ushortT* outp = (by < 4) ? ps : ((by < 8) ? pt : fcp);
  const int col0 = (by & 3) * 64;
  const int n0 = by * 64;

  const int tid = threadIdx.x;
  const int wave = tid >> 6;
  const int lane = tid & 63;
  const int quad = lane >> 4;
  const int l16 = lane & 15;

  const int m_base_t = (wave & 1) * 32;
  const int wn = wave >> 1;

  {
    const int rl = lane >> 5;
    const int cph = lane & 31;
#pragma unroll
    for (int c = 0; c < 8; ++c) {
      const int r = wave * 16 + c * 2 + rl;
      const int clog = cph ^ (r & 7);
      gload16(featb + (size_t)(m0 + r) * D + clog * 8, &Als[wave * 16 + c * 2][0]);
      gload16(Wcat + (size_t)(n0 + r) * D + clog * 8, &Bls[wave * 16 + c * 2][0]);
    }
  }
  __syncthreads();

  f32x4 acc[2][2];
#pragma unroll
  for (int i = 0; i < 2; ++i)
#pragma unroll
    for (int j = 0; j < 2; ++j) acc[i][j] = (f32x4){0.f, 0.f, 0.f, 0.f};

  const int ar0 = m_base_t + l16;
  const int br0 = wn * 32 + l16;
  const int xa = ar0 & 7;
  const int xb = br0 & 7;
#pragma unroll
  for (int kk = 0; kk < 8; ++kk) {
    const int j = kk * 4 + quad;
    const int ea = (j ^ xa) * 8;
    const int eb = (j ^ xb) * 8;
    bf16x8 a0 = *(const bf16x8*)&Als[ar0][ea];
    bf16x8 a1 = *(const bf16x8*)&Als[ar0 + 16][ea];
    bf16x8 b0 = *(const bf16x8*)&Bls[br0][eb];
    bf16x8 b1 = *(const bf16x8*)&Bls[br0 + 16][eb];
    acc[0][0] = __builtin_amdgcn_mfma_f32_16x16x32_bf16(a0, b0, acc[0][0], 0, 0, 0);
    acc[0][1] = __builtin_amdgcn_mfma_f32_16x16x32_bf16(a0, b1, acc[0][1], 0, 0, 0);
    acc[1][0] = __builtin_amdgcn_mfma_f32_16x16x32_bf16(a1, b0, acc[1][0], 0, 0, 0);
    acc[1][1] = __builtin_amdgcn_mfma_f32_16x16x32_bf16(a1, b1, acc[1][1], 0, 0, 0);
  }

  // C/D layout: col = lane&15, row = quad*4 + reg [m89/m91]
#pragma unroll
  for (int mi = 0; mi < 2; ++mi)
#pragma unroll
    for (int r = 0; r < 4; ++r) {
      const int row = m_base_t + mi * 16 + quad * 4 + r;
#pragma unroll
      for (int ni = 0; ni < 2; ++ni)
        Cls[row][wn * 32 + ni * 16 + l16] = f2bf(acc[mi][ni][r]);
    }
  __syncthreads();
#pragma unroll
  for (int it = 0; it < 2; ++it) {
    const int idx = tid + it * 256;
    const int row = idx >> 3;
    const int cc = (idx & 7) * 8;
    const int grow = m0 + row;
    if (grow < N_NODES)
      *(bf16x8*)(outp + (size_t)grow * D + col0 + cc) = *(const bf16x8*)&Cls[row][cc];
  }
}

// Wave per node (R2 structure); pair-unpack inner loop (1 VALU/elem).
__global__ __launch_bounds__(256) void logit_bucket_kernel(
    const ushortT* __restrict__ ps,
    const ushortT* __restrict__ pt,
    const int* __restrict__ cnt,
    const int* __restrict__ src_b,
    const float* __restrict__ Wattn,
    float* __restrict__ expv_b,
    float* __restrict__ denom) {
  const int wave = threadIdx.x >> 6;
  const int n = blockIdx.x * 4 + wave;
  if (n >= N_NODES) return;
  const int cn = min(cnt[n], BCAP);
  if (cn == 0) return;
  const int lane = threadIdx.x & 63;
  const int half = lane >> 5;
  const int l32 = lane & 31;
  const int base = n * BCAP;

  const int4 bw = *(const int4*)(pt + (size_t)n * D + l32 * 8);
  float b[8], w[8];
  const float4 w0 = *(const float4*)(Wattn + l32 * 8);
  const float4 w1 = *(const float4*)(Wattn + l32 * 8 + 4);
  w[0] = w0.x; w[1] = w0.y; w[2] = w0.z; w[3] = w0.w;
  w[4] = w1.x; w[5] = w1.y; w[6] = w1.z; w[7] = w1.w;
  b[0] = blo(bw.x); b[1] = bhi(bw.x); b[2] = blo(bw.y); b[3] = bhi(bw.y);
  b[4] = blo(bw.z); b[5] = bhi(bw.z); b[6] = blo(bw.w); b[7] = bhi(bw.w);

  int j = half;
  for (; j + 6 < cn; j += 8) {
    const int s0 = src_b[base + j];
    const int s1 = src_b[base + j + 2];
    const int s2 = src_b[base + j + 4];
    const int s3 = src_b[base + j + 6];
    const int4 q0 = *(const int4*)(ps + (size_t)s0 * D + l32 * 8);
    const int4 q1 = *(const int4*)(ps + (size_t)s1 * D + l32 * 8);
    const int4 q2 = *(const int4*)(ps + (size_t)s2 * D + l32 * 8);
    const int4 q3 = *(const int4*)(ps + (size_t)s3 * D + l32 * 8);
    const int w0q[4] = {q0.x, q0.y, q0.z, q0.w};
    const int w1q[4] = {q1.x, q1.y, q1.z, q1.w};
    const int w2q[4] = {q2.x, q2.y, q2.z, q2.w};
    const int w3q[4] = {q3.x, q3.y, q3.z, q3.w};
    float sum0 = 0.f, sum1 = 0.f, sum2 = 0.f, sum3 = 0.f;
#pragma unroll
    for (int k = 0; k < 4; ++k) {
      float z;
      z = blo(w0q[k]) + b[2 * k];     z = fmaxf(z, NEG_SLOPE * z); sum0 = fmaf(w[2 * k], z, sum0);
      z = bhi(w0q[k]) + b[2 * k + 1]; z = fmaxf(z, NEG_SLOPE * z); sum0 = fmaf(w[2 * k + 1], z, sum0);
      z = blo(w1q[k]) + b[2 * k];     z = fmaxf(z, NEG_SLOPE * z); sum1 = fmaf(w[2 * k], z, sum1);
      z = bhi(w1q[k]) + b[2 * k + 1]; z = fmaxf(z, NEG_SLOPE * z); sum1 = fmaf(w[2 * k + 1], z, sum1);
      z = blo(w2q[k]) + b[2 * k];     z = fmaxf(z, NEG_SLOPE * z); sum2 = fmaf(w[2 * k], z, sum2);
      z = bhi(w2q[k]) + b[2 * k + 1]; z = fmaxf(z, NEG_SLOPE * z); sum2 = fmaf(w[2 * k + 1], z, sum2);
      z = blo(w3q[k]) + b[2 * k];     z = fmaxf(z, NEG_SLOPE * z); sum3 = fmaf(w[2 * k], z, sum3);
      z = bhi(w3q[k]) + b[2 * k + 1]; z = fmaxf(z, NEG_SLOPE * z); sum3 = fmaf(w[2 * k + 1], z, sum3);
    }
#pragma unroll
    for (int off = 16; off > 0; off >>= 1) {
      sum0 += __shfl_down(sum0, off, 32);
      sum1 += __shfl_down(sum1, off, 32);
      sum2 += __shfl_down(sum2, off, 32);
      sum3 += __shfl_down(sum3, off, 32);
    }
    if (l32 == 0) {
      float ex0 = __expf(sum0), ex1 = __expf(sum1);
      float ex2 = __expf(sum2), ex3 = __expf(sum3);
      expv_b[base + j] = ex0;
      expv_b[base + j + 2] = ex1;
      expv_b[base + j + 4] = ex2;
      expv_b[base + j + 6] = ex3;
      atomicAdd(&denom[s0], ex0);
      atomicAdd(&denom[s1], ex1);
      atomicAdd(&denom[s2], ex2);
      atomicAdd(&denom[s3], ex3);
    }
  }
  for (; j < cn; j += 2) {
    const int s = src_b[base + j];
    const int4 q = *(const int4*)(ps + (size_t)s * D + l32 * 8);
    const int wq[4] = {q.x, q.y, q.z, q.w};
    float sum = 0.f;
#pragma unroll
    for (int k = 0; k < 4; ++k) {
      float z;
      z = blo(wq[k]) + b[2 * k];     z = fmaxf(z, NEG_SLOPE * z); sum = fmaf(w[2 * k], z, sum);
      z = bhi(wq[k]) + b[2 * k + 1]; z = fmaxf(z, NEG_SLOPE * z); sum = fmaf(w[2 * k + 1], z, sum);
    }
#pragma unroll
    for (int off = 16; off > 0; off >>= 1) sum += __shfl_down(sum, off, 32);
    if (l32 == 0) {
      float ex = __expf(sum);
      expv_b[base + j] = ex;
      atomicAdd(&denom[s], ex);
    }
  }
}

// Wave per node (R2 structure); pair-unpack + v_rcp alpha.
__global__ __launch_bounds__(256) void gather_agg_kernel(
    const ushortT* __restrict__ fcp,
    const int* __restrict__ cnt,
    const int* __restrict__ src_b,
    const float* __restrict__ expv_b,
    const float* __restrict__ denom,
    const float* __restrict__ b_fc,
    float* __restrict__ out) {
  const int wave = threadIdx.x >> 6;
  const int n = blockIdx.x * 4 + wave;
  if (n >= N_NODES) return;
  const int lane = threadIdx.x & 63;
  const int half = lane >> 5;
  const int l32 = lane & 31;
  const int cn = min(cnt[n], BCAP);
  const int base = n * BCAP;

  float acc[8];
#pragma unroll
  for (int i = 0; i < 8; ++i) acc[i] = 0.f;

  int j = half;
  for (; j + 6 < cn; j += 8) {
    const int s0 = src_b[base + j];
    const int s1 = src_b[base + j + 2];
    const int s2 = src_b[base + j + 4];
    const int s3 = src_b[base + j + 6];
    const float a0 = expv_b[base + j] * fastrcp(denom[s0]);
    const float a1 = expv_b[base + j + 2] * fastrcp(denom[s1]);
    const float a2 = expv_b[base + j + 4] * fastrcp(denom[s2]);
    const float a3 = expv_b[base + j + 6] * fastrcp(denom[s3]);
    const int4 q0 = *(const int4*)(fcp + (size_t)s0 * D + l32 * 8);
    const int4 q1 = *(const int4*)(fcp + (size_t)s1 * D + l32 * 8);
    const int4 q2 = *(const int4*)(fcp + (size_t)s2 * D + l32 * 8);
    const int4 q3 = *(const int4*)(fcp + (size_t)s3 * D + l32 * 8);
    const int w0q[4] = {q0.x, q0.y, q0.z, q0.w};
    const int w1q[4] = {q1.x, q1.y, q1.z, q1.w};
    const int w2q[4] = {q2.x, q2.y, q2.z, q2.w};
    const int w3q[4] = {q3.x, q3.y, q3.z, q3.w};
#pragma unroll
    for (int k = 0; k < 4; ++k) {
      acc[2 * k]     = fmaf(a0, blo(w0q[k]), acc[2 * k]);
      acc[2 * k + 1] = fmaf(a0, bhi(w0q[k]), acc[2 * k + 1]);
      acc[2 * k]     = fmaf(a1, blo(w1q[k]), acc[2 * k]);
      acc[2 * k + 1] = fmaf(a1, bhi(w1q[k]), acc[2 * k + 1]);
      acc[2 * k]     = fmaf(a2, blo(w2q[k]), acc[2 * k]);
      acc[2 * k + 1] = fmaf(a2, bhi(w2q[k]), acc[2 * k + 1]);
      acc[2 * k]     = fmaf(a3, blo(w3q[k]), acc[2 * k]);
      acc[2 * k + 1] = fmaf(a3, bhi(w3q[k]), acc[2 * k + 1]);
    }
  }
  for (; j < cn; j += 2) {
    const int s = src_b[base + j];
    const float a = expv_b[base + j] * fastrcp(denom[s]);
    const int4 q = *(const int4*)(fcp + (size_t)s * D + l32 * 8);
    const int wq[4] = {q.x, q.y, q.z, q.w};
#pragma unroll
    for (int k = 0; k < 4; ++k) {
      acc[2 * k]     = fmaf(a, blo(wq[k]), acc[2 * k]);
      acc[2 * k + 1] = fmaf(a, bhi(wq[k]), acc[2 * k + 1]);
    }
  }
#pragma unroll
  for (int i = 0; i < 8; ++i) acc[i] += __shfl_xor(acc[i], 32);
  if (half == 0) {
    const float4 bf0 = *(const float4*)(b_fc + l32 * 8);
    const float4 bf1 = *(const float4*)(b_fc + l32 * 8 + 4);
    float4 o0 = make_float4(acc[0] + bf0.x, acc[1] + bf0.y, acc[2] + bf0.z, acc[3] + bf0.w);
    float4 o1 = make_float4(acc[4] + bf1.x, acc[5] + bf1.y, acc[6] + bf1.z, acc[7] + bf1.w);
    *(float4*)(out + (size_t)n * D + l32 * 8) = o0;
    *(float4*)(out + (size_t)n * D + l32 * 8 + 4) = o1;
  }
}

extern "C" void kernel_launch(void* const* d_in, const int* in_sizes, int n_in,
                              void* d_out, int out_size, void* d_ws, size_t ws_size,
                              hipStream_t stream) {
  const float* feat  = (const float*)d_in[0];
  const int*   src   = (const int*)d_in[1];
  const int*   dst   = (const int*)d_in[2];
  const float* Ws    = (const float*)d_in[3];
  const float* Wt    = (const float*)d_in[4];
  const float* Wattn = (const float*)d_in[5];
  const float* Wfc   = (const float*)d_in[6];
  const float* bfc   = (const float*)d_in[7];
  float* out = (float*)d_out;

  ushortT* ps    = (ushortT*)d_ws;
  ushortT* pt    = ps + (size_t)N_NODES * D;
  ushortT* fcp   = pt + (size_t)N_NODES * D;
  ushortT* featb = fcp + (size_t)N_NODES * D;
  ushortT* Wcat  = featb + (size_t)N_NODES * D;
  float* expv_b  = (float*)(Wcat + (size_t)768 * 256);
  float* denom   = expv_b + (size_t)N_NODES * BCAP;
  int*   cnt     = (int*)(denom + N_NODES);
  int*   src_b   = cnt + N_NODES;

  const int prep_items = NF4 + 3 * NW4 + N_NODES;
  const int nodeblocks = (N_NODES + 3) / 4;
  prep_kernel<<<(prep_items + BLOCK - 1) / BLOCK, BLOCK, 0, stream>>>(
      feat, Ws, Wt, Wfc, featb, Wcat, cnt, denom);
  proj_fill_kernel<<<FILL_BLOCKS + NTILES, BLOCK, 0, stream>>>(
      featb, Wcat, src, dst, cnt, src_b, ps, pt, fcp);
  logit_bucket_kernel<<<nodeblocks, BLOCK, 0, stream>>>(ps, pt, cnt, src_b, Wattn, expv_b, denom);
  gather_agg_kernel<<<nodeblocks, BLOCK, 0, stream>>>(fcp, cnt, src_b, expv_b, denom, bfc, out);
}